// Round 15
// baseline (335.038 us; speedup 1.0000x reference)
//
#include <hip/hip_runtime.h>

typedef short s8v __attribute__((ext_vector_type(8)));
typedef float f4v __attribute__((ext_vector_type(4)));

#define MFMA16(a,b,c) __builtin_amdgcn_mfma_f32_16x16x32_bf16(a,b,c,0,0,0)

#define TOK 36864
#define SEQ 9216
#define CH 128
#define WL 2304
#define ATTN_SCALE (1.0f/1179648.0f)

__device__ __forceinline__ float b2f(unsigned short u){
  union{unsigned i; float f;} c; c.i = ((unsigned)u)<<16; return c.f;
}
__device__ __forceinline__ unsigned short f2b(float f){
  union{float f; unsigned i;} c; c.f = f;
  unsigned r = c.i + 0x7fffu + ((c.i>>16)&1u);
  return (unsigned short)(r>>16);
}
// window (g,pos) -> token (inverse of the roll+split map)
__device__ __forceinline__ int wtok(int g, int pos){
  int bi = g>>2, ih = (g>>1)&1, iw = g&1;
  int rr = pos/48, ss = pos - rr*48;
  int p = ih*48 + rr, q = iw*48 + ss;
  int i = p + 24; if (i >= 96) i -= 96;
  int j = q + 24; if (j >= 96) j -= 96;
  return bi*SEQ + i*96 + j;
}

// ---------------- K0: weight transpose f32->bf16 + param pack ----------------
__global__ __launch_bounds__(256) void k_prep(const float* __restrict__ wgq,
    const float* __restrict__ wkv, const float* __restrict__ wo1, const float* __restrict__ wo2,
    const float* __restrict__ bgq, const float* __restrict__ bkv, const float* __restrict__ bo1,
    const float* __restrict__ lng, const float* __restrict__ lnb,
    unsigned short* __restrict__ Wt, unsigned short* __restrict__ Wt1,
    unsigned short* __restrict__ Wt2, unsigned short* __restrict__ P)
{
  int idx = blockIdx.x*256 + threadIdx.x;
  if (idx < 65536){
    int n = idx>>7, k = idx&127;
    Wt[idx] = f2b((n<256) ? wgq[k*256+n] : wkv[k*256+(n-256)]);
  } else if (idx < 81920){
    int t2 = idx-65536; int n = t2>>7, k = t2&127;
    Wt1[t2] = f2b(wo1[k*128+n]);
  } else if (idx < 98304){
    int t2 = idx-81920; int n = t2>>7, k = t2&127;
    Wt2[t2] = f2b(wo2[k*128+n]);
  } else if (idx < 99200){
    int j = idx-98304;
    float v;
    if (j<256)      v = bgq[j];
    else if (j<512) v = bkv[j-256];
    else if (j<640) v = bo1[j-512];
    else if (j<768) v = lng[j-640];
    else            v = lnb[j-768];
    P[j] = f2b(v);   // P: [bgq|bkv|bo1|lng|lnb]
  }
}

// ---------------- K1: fused LN + projection GEMM + silu ----------------
// Round 8 version (validated: 66 -> ~35 µs): weight sub-tile staged in a
// XOR-swizzled [128][128] LDS tile (coalesced 1KB/instr loads, swizzled
// b128 fragment reads). Grid (576,2); 2 sub-chunks per block.
__global__ __launch_bounds__(256) void k_proj(const float* __restrict__ src,
    const unsigned short* __restrict__ Wt, const unsigned short* __restrict__ P,
    float* __restrict__ gate, unsigned short* __restrict__ Qw,
    unsigned short* __restrict__ Kw, unsigned short* __restrict__ Vb)
{
  __shared__ __align__(16) short lS[64][136];
  __shared__ __align__(16) short lW[128][128];   // weight sub-tile, swizzled
  const int tid = threadIdx.x;
  const int w = tid>>6, l = tid&63, l16 = l&15, quad = l>>4;
  const int m0 = blockIdx.x*64;
  const int chunk = blockIdx.y;

  { // LayerNorm of 64 rows into LDS (4 threads per row)
    int row = tid>>2, lam = tid&3;
    const float* sp = src + (m0+row)*CH + lam*32;
    float v[32]; float s = 0.f, sq = 0.f;
#pragma unroll
    for (int j=0;j<32;j++){ v[j] = sp[j]; s += v[j]; sq += v[j]*v[j]; }
    s += __shfl_xor(s,1); sq += __shfl_xor(sq,1);
    s += __shfl_xor(s,2); sq += __shfl_xor(sq,2);
    float mean = s*(1.f/128.f);
    float rstd = rsqrtf(sq*(1.f/128.f) - mean*mean + 1e-5f);
#pragma unroll
    for (int j=0;j<32;j++){
      int c = lam*32 + j;
      lS[row][c] = (short)f2b((v[j]-mean)*rstd*b2f(P[640+c]) + b2f(P[768+c]));
    }
  }
  __syncthreads();

  s8v a[4];
#pragma unroll
  for (int kc=0;kc<4;kc++) a[kc] = *(const s8v*)&lS[w*16+l16][kc*32+quad*8];

  int tokv[4], gidx[4], posv[4];
#pragma unroll
  for (int r=0;r<4;r++){
    int token = m0 + w*16 + quad*4 + r;
    int bi = token / SEQ; int t = token - bi*SEQ;
    int i = t / 96; int j = t - i*96;
    int p = i - 24; if (p<0) p += 96;
    int q = j - 24; if (q<0) q += 96;
    int ihh = (p>=48); int rr = p - ihh*48;
    int iww = (q>=48); int ss = q - iww*48;
    tokv[r] = token;
    gidx[r] = bi*4 + ihh*2 + iww;
    posv[r] = rr*48 + ss;
  }

  // weight staging geometry (k_attn lK recipe): rows j*16+kr0, coalesced
  const int kr0 = tid>>4, kc0 = (tid&15)*8;
  const int kws = ((tid&15) ^ (kr0&7))*8;        // swizzled chunk (row&7 == kr0&7)
  const unsigned short* Wsrc = Wt + (chunk*256)*CH;

  for (int sc=0; sc<2; sc++){
    const unsigned short* wp = Wsrc + (sc*128 + kr0)*CH + kc0;
#pragma unroll
    for (int j=0;j<8;j++)
      *(s8v*)&lW[j*16 + kr0][kws] = *(const s8v*)(wp + j*16*CH);
    __syncthreads();

    f4v acc[8];
#pragma unroll
    for (int nt=0;nt<8;nt++){
      f4v z = {0.f,0.f,0.f,0.f}; acc[nt] = z;
#pragma unroll
      for (int kc=0;kc<4;kc++)
        acc[nt] = MFMA16(a[kc],
                         *(const s8v*)&lW[nt*16+l16][((kc*4+quad) ^ (l16&7))*8],
                         acc[nt]);
    }
#pragma unroll
    for (int nt=0;nt<8;nt++){
      int col = chunk*256 + sc*128 + nt*16 + l16;
      float bias = b2f(P[col]);
#pragma unroll
      for (int r=0;r<4;r++){
        float z = acc[nt][r] + bias;
        z = z / (1.0f + __expf(-z));            // silu
        if (col < 128){
          gate[tokv[r]*CH + col] = z;           // f32, parked in d_out
        } else if (col < 256){
          Qw[(gidx[r]*WL + posv[r])*CH + (col-128)] = f2b(z);
        } else if (col < 384){
          Kw[(gidx[r]*WL + posv[r])*CH + (col-256)] = f2b(z);
        } else {
          Vb[tokv[r]*CH + (col-384)] = f2b(z);  // token-layout (k_vt transposes)
        }
      }
    }
    __syncthreads();   // lW reads done before next stage
  }
}

// ---------------- K1b: V token-layout -> windowed V^T [g][ch][pos] ----------------
// Conflict-free LDS transpose (pitch 66 shorts): stage bank=lane, read bank=33*key≡key.
__global__ __launch_bounds__(256) void k_vt(const unsigned short* __restrict__ Vb,
    unsigned short* __restrict__ Vt)
{
  __shared__ short lR[64*66];
  const int tid = threadIdx.x;
  const int g = blockIdx.y;
  const int q0 = blockIdx.x*64;
  const int lane = tid&63, grp = tid>>6;
#pragma unroll 4
  for (int p=0;p<16;p++){
    int key = p*4 + grp;
    int token = wtok(g, q0+key);
    unsigned v = *(const unsigned*)(Vb + token*CH + lane*2);   // 2 ch per lane
    *(unsigned*)&lR[key*66 + lane*2] = v;
  }
  __syncthreads();
#pragma unroll 8
  for (int i=0;i<32;i++){
    int ch = grp*32 + i;
    Vt[g*CH*WL + ch*WL + q0 + lane] = (unsigned short)lR[lane*66 + ch];
  }
}

// ---------------- K2: windowed attention, BM=64, DOUBLE-BUFFERED ----------------
// Round 15: lK/lV double-buffered -> ONE barrier per k-iteration (was two with
// the 8-op staging write fully exposed between them; MfmaUtil+VALUBusy = 45%
// meant ~55% barrier/waitcnt stall). Staging write moves AFTER compute where
// it overlaps other waves' MFMA. Per-thread arithmetic, operand bytes, and
// accumulation order UNCHANGED (address/barrier-only change).
// LDS 40 -> 72 KB (2 blocks/CU vs 2.25 avg).
//  (a) XOR-swizzled LDS tiles; (b) s_setprio around MFMA clusters;
//  (c) rule-#18 fence after the lP wave-drain (race proven & fixed in r12).
// attn aliases Qw: each block reads exactly the Q rows it later writes.
__global__ __launch_bounds__(256, 2) void k_attn(const unsigned short* Qw,
    const unsigned short* __restrict__ Kw, const unsigned short* __restrict__ Vt,
    unsigned short* attn)
{
  __shared__ __align__(16) short lK[2][64][128];   // K tiles [buf][key][ch], swizzled
  __shared__ __align__(16) short lV[2][128][64];   // V tiles [buf][ch][key], swizzled
  __shared__ __align__(16) short lP[4][16][64];    // per-wave P [row][key], swizzled
  const int tid = threadIdx.x;
  const int w = tid>>6, l = tid&63, l16 = l&15, quad = l>>4;

  // XCD swizzle: bijective since 576 % 8 == 0
  const int n  = blockIdx.x;
  const int L  = (n & 7)*72 + (n >> 3);
  const int g  = L/36;
  const int q0 = (L - g*36)*64;
  const int ih = (g>>1)&1, iw = g&1;

  const unsigned short* qp = Qw + (g*WL + q0 + w*16 + l16)*CH + quad*8;
  s8v aQ[4];
#pragma unroll
  for (int kc=0;kc<4;kc++) aQ[kc] = *(const s8v*)(qp + kc*32);

  int qrl[4], qcl[4];
#pragma unroll
  for (int r=0;r<4;r++){
    int qpj = q0 + w*16 + quad*4 + r;
    int qr = qpj/48, qs = qpj - qr*48;
    qrl[r] = (qr>=24); qcl[r] = (qs>=24);
  }

  // staging geometry + swizzled LDS chunk indices (constant per thread)
  const int kr0 = tid>>4, kc0 = (tid&15)*8;        // K: rows kr0+it*16, global chans kc0..+7
  const int vc0 = tid>>3, vp0 = (tid&7)*8;         // V: chans vc0+it*32, global keys vp0..+7
  const int kws = ((tid&15) ^ (kr0&7))*8;          // lK swizzled short offset (row&7 == kr0&7)
  const int vws = ((tid&7)  ^ (vc0&7))*8;          // lV swizzled short offset (row&7 == vc0&7)
  const unsigned short* Kbase = Kw + g*WL*CH;
  const unsigned short* Vbase = Vt + g*CH*WL;
  s8v rK[4], rV[4];

#define LOAD_TILE(kk) do { \
    const unsigned short* Kg_ = Kbase + (kk)*CH; \
    const unsigned short* Vg_ = Vbase + (kk); \
    rK[0] = *(const s8v*)(Kg_ + (kr0+ 0)*CH + kc0); \
    rK[1] = *(const s8v*)(Kg_ + (kr0+16)*CH + kc0); \
    rK[2] = *(const s8v*)(Kg_ + (kr0+32)*CH + kc0); \
    rK[3] = *(const s8v*)(Kg_ + (kr0+48)*CH + kc0); \
    rV[0] = *(const s8v*)(Vg_ + (vc0+ 0)*WL + vp0); \
    rV[1] = *(const s8v*)(Vg_ + (vc0+32)*WL + vp0); \
    rV[2] = *(const s8v*)(Vg_ + (vc0+64)*WL + vp0); \
    rV[3] = *(const s8v*)(Vg_ + (vc0+96)*WL + vp0); \
  } while(0)

#define WRITE_TILE(b) do { \
    *(s8v*)&lK[b][kr0+ 0][kws] = rK[0]; \
    *(s8v*)&lK[b][kr0+16][kws] = rK[1]; \
    *(s8v*)&lK[b][kr0+32][kws] = rK[2]; \
    *(s8v*)&lK[b][kr0+48][kws] = rK[3]; \
    *(s8v*)&lV[b][vc0+ 0][vws] = rV[0]; \
    *(s8v*)&lV[b][vc0+32][vws] = rV[1]; \
    *(s8v*)&lV[b][vc0+64][vws] = rV[2]; \
    *(s8v*)&lV[b][vc0+96][vws] = rV[3]; \
  } while(0)

  f4v O[8];
#pragma unroll
  for (int i=0;i<8;i++){ f4v z = {0.f,0.f,0.f,0.f}; O[i] = z; }
  float lsum[4] = {0.f,0.f,0.f,0.f};

  // prologue: tile 0 staged to buf0; tile 1 prefetched into regs
  LOAD_TILE(0);
  WRITE_TILE(0);
  LOAD_TILE(64);
  __syncthreads();

  for (int k0=0; k0<WL; k0+=64){
    const int cur = (k0>>6)&1;

    f4v S[4];
    __builtin_amdgcn_s_setprio(1);
#pragma unroll
    for (int nt=0;nt<4;nt++){
      f4v z = {0.f,0.f,0.f,0.f}; S[nt] = z;
#pragma unroll
      for (int kc=0;kc<4;kc++)
        S[nt] = MFMA16(aQ[kc],
                       *(const s8v*)&lK[cur][nt*16+l16][((kc*4+quad) ^ (l16&7))*8],
                       S[nt]);
    }
    __builtin_amdgcn_s_setprio(0);

#pragma unroll
    for (int nt=0;nt<4;nt++){
      int key = k0 + nt*16 + l16;
      int kr = key/48, ks = key - kr*48;
      int krl = (kr>=24), kcl = (ks>=24);
#pragma unroll
      for (int r=0;r<4;r++){
        bool masked = (ih && (krl != qrl[r])) || (iw && (kcl != qcl[r]));
        float p = masked ? 0.0f : __expf(S[nt][r]*ATTN_SCALE);
        unsigned short pb = f2b(p);
        lsum[r] += b2f(pb);
        // element (row=quad*4+r, key short s=nt*16+l16) at chunk (s>>3)^(row&7)
        lP[w][quad*4+r][(((nt*2)+(l16>>3)) ^ ((quad*4+r)&7))*8 + (l16&7)] = (short)pb;
      }
    }
    // P is wave-private: drain LDS writes, then fence the scheduler (rule #18)
    asm volatile("s_waitcnt lgkmcnt(0)" ::: "memory");
    __builtin_amdgcn_sched_barrier(0);

    __builtin_amdgcn_s_setprio(1);
#pragma unroll
    for (int kc2=0;kc2<2;kc2++){
      s8v aP = *(const s8v*)&lP[w][l16][((kc2*4+quad) ^ (l16&7))*8];
#pragma unroll
      for (int nt=0;nt<8;nt++)
        O[nt] = MFMA16(aP,
                       *(const s8v*)&lV[cur][nt*16+l16][((kc2*4+quad) ^ (l16&7))*8],
                       O[nt]);
    }
    __builtin_amdgcn_s_setprio(0);

    // stage tile k0+64 into the other buffer (regs already loaded), then
    // prefetch tile k0+128 into regs. ONE barrier: ensures (a) all waves done
    // computing buf[cur] before next iter overwrites it, (b) buf[cur^1] writes
    // visible before next iter reads it.
    if (k0+64 < WL){
      WRITE_TILE(cur^1);
      if (k0+128 < WL) LOAD_TILE(k0+128);
      __syncthreads();
    }
  }

#undef LOAD_TILE
#undef WRITE_TILE

#pragma unroll
  for (int r=0;r<4;r++){
#pragma unroll
    for (int m=1;m<16;m<<=1) lsum[r] += __shfl_xor(lsum[r], m);
  }
  unsigned short* outp = attn + (g*WL + q0 + w*16)*CH;
#pragma unroll
  for (int nt=0;nt<8;nt++){
#pragma unroll
    for (int r=0;r<4;r++)
      outp[(quad*4+r)*CH + nt*16 + l16] = f2b(O[nt][r] / lsum[r]);
  }
}

// ---------------- K3: unwindow + gate + o1(silu) + o2 + residual (f32 out) ----------------
// Round 14 version (banked: staged weights, full barriers around the lW
// rewrite; passed with fenced k_attn).
__global__ __launch_bounds__(256) void k_out(const unsigned short* __restrict__ attn,
    const unsigned short* __restrict__ Wo1, const unsigned short* __restrict__ P,
    const unsigned short* __restrict__ Wo2, const float* __restrict__ src,
    float* out)
{
  __shared__ __align__(16) short lA[64][136];
  __shared__ __align__(16) short lU[4][16][136];
  __shared__ __align__(16) short lW[128][128];   // weight tile, swizzled (Wo1 then Wo2)
  const int tid = threadIdx.x;
  const int w = tid>>6, l = tid&63, l16 = l&15, quad = l>>4;
  const int m0 = blockIdx.x*64;

  // weight staging geometry (r8-validated recipe)
  const int kr0 = tid>>4, kc0 = (tid&15)*8;
  const int kws = ((tid&15) ^ (kr0&7))*8;        // swizzled chunk (row&7 == kr0&7)

  {
    int r_loc = tid>>2;
    int cb = (tid&3)*32;
    int token = m0 + r_loc;
    int bi = token / SEQ; int t = token - bi*SEQ;
    int i = t / 96; int j = t - i*96;
    int p = i - 24; if (p<0) p += 96;
    int q = j - 24; if (q<0) q += 96;
    int ihh = (p>=48); int rr = p - ihh*48;
    int iww = (q>=48); int ss = q - iww*48;
    int wb = (bi*4 + ihh*2 + iww)*WL + rr*48 + ss;
    const unsigned short* av = attn + wb*CH + cb;
    const float* gv = out + token*CH + cb;    // gate parked in out[0:TOK*CH)
#pragma unroll
    for (int u=0;u<4;u++){
      s8v a8 = *(const s8v*)(av + u*8);
      float4 g0 = *(const float4*)(gv + u*8);
      float4 g1 = *(const float4*)(gv + u*8 + 4);
      s8v o;
      o[0]=(short)f2b(b2f((unsigned short)a8[0])*g0.x);
      o[1]=(short)f2b(b2f((unsigned short)a8[1])*g0.y);
      o[2]=(short)f2b(b2f((unsigned short)a8[2])*g0.z);
      o[3]=(short)f2b(b2f((unsigned short)a8[3])*g0.w);
      o[4]=(short)f2b(b2f((unsigned short)a8[4])*g1.x);
      o[5]=(short)f2b(b2f((unsigned short)a8[5])*g1.y);
      o[6]=(short)f2b(b2f((unsigned short)a8[6])*g1.z);
      o[7]=(short)f2b(b2f((unsigned short)a8[7])*g1.w);
      *(s8v*)&lA[r_loc][cb + u*8] = o;
    }
  }
  { // stage Wo1 into lW (coalesced 1KB/instr, swizzled dest)
    const unsigned short* wp = Wo1 + kr0*CH + kc0;
#pragma unroll
    for (int j=0;j<8;j++)
      *(s8v*)&lW[j*16 + kr0][kws] = *(const s8v*)(wp + j*16*CH);
  }
  __syncthreads();

  s8v aA[4];
#pragma unroll
  for (int kc=0;kc<4;kc++) aA[kc] = *(const s8v*)&lA[w*16+l16][kc*32+quad*8];
  f4v acc[8];
#pragma unroll
  for (int nt=0;nt<8;nt++){
    f4v z = {0.f,0.f,0.f,0.f}; acc[nt] = z;
#pragma unroll
    for (int kc=0;kc<4;kc++)
      acc[nt] = MFMA16(aA[kc],
                       *(const s8v*)&lW[nt*16+l16][((kc*4+quad) ^ (l16&7))*8],
                       acc[nt]);
  }
#pragma unroll
  for (int nt=0;nt<8;nt++){
    int col = nt*16 + l16;
    float bias = b2f(P[512+col]);   // bo1
#pragma unroll
    for (int r=0;r<4;r++){
      float z = acc[nt][r] + bias;
      z = z / (1.0f + __expf(-z));
      lU[w][quad*4+r][col] = (short)f2b(z);
    }
  }
  __syncthreads();   // all lW(Wo1) reads + lU writes drained (barrier waits lgkmcnt(0))

  { // stage Wo2 into lW (safe: previous reads complete across the barrier)
    const unsigned short* wp = Wo2 + kr0*CH + kc0;
#pragma unroll
    for (int j=0;j<8;j++)
      *(s8v*)&lW[j*16 + kr0][kws] = *(const s8v*)(wp + j*16*CH);
  }
  __syncthreads();   // lW(Wo2) visible

  s8v aU[4];
#pragma unroll
  for (int kc=0;kc<4;kc++) aU[kc] = *(const s8v*)&lU[w][l16][kc*32+quad*8];
  f4v acc2[8];
#pragma unroll
  for (int nt=0;nt<8;nt++){
    f4v z = {0.f,0.f,0.f,0.f}; acc2[nt] = z;
#pragma unroll
    for (int kc=0;kc<4;kc++)
      acc2[nt] = MFMA16(aU[kc],
                        *(const s8v*)&lW[nt*16+l16][((kc*4+quad) ^ (l16&7))*8],
                        acc2[nt]);
  }
#pragma unroll
  for (int nt=0;nt<8;nt++){
#pragma unroll
    for (int r=0;r<4;r++){
      int token = m0 + w*16 + quad*4 + r;
      int col = nt*16 + l16;
      float y = acc2[nt][r] + src[token*CH + col];
      out[token*CH + col] = y;
      out[TOK*CH + token*CH + col] = y;
    }
  }
}

extern "C" void kernel_launch(void* const* d_in, const int* in_sizes, int n_in,
                              void* d_out, int out_size, void* d_ws, size_t ws_size,
                              hipStream_t stream)
{
  const float* src = (const float*)d_in[0];
  const float* lng = (const float*)d_in[5];
  const float* lnb = (const float*)d_in[6];
  const float* wgq = (const float*)d_in[7];
  const float* bgq = (const float*)d_in[8];
  const float* wkv = (const float*)d_in[9];
  const float* bkv = (const float*)d_in[10];
  const float* wo1 = (const float*)d_in[11];
  const float* bo1 = (const float*)d_in[12];
  const float* wo2 = (const float*)d_in[13];

  // Workspace 36.2 MiB: P | Wt | Wt1 | Wt2 | Qw(attn overlays) | Kw | Vt | Vb
  char* ws = (char*)d_ws;
  unsigned short* P   = (unsigned short*)(ws);
  unsigned short* Wt  = (unsigned short*)(ws + 2048);
  unsigned short* Wt1 = (unsigned short*)(ws + 133120);
  unsigned short* Wt2 = (unsigned short*)(ws + 165888);
  unsigned short* Qw  = (unsigned short*)(ws + 198656);    // window layout
  unsigned short* Kw  = (unsigned short*)(ws + 9635840);   // window layout
  unsigned short* Vt  = (unsigned short*)(ws + 19073024);  // [g][ch][pos]
  unsigned short* Vb  = (unsigned short*)(ws + 28510208);  // token layout
  float* out = (float*)d_out;                              // gate in out[0:TOK*CH)

  k_prep<<<dim3(388),   dim3(256), 0, stream>>>(wgq, wkv, wo1, wo2, bgq, bkv, bo1, lng, lnb,
                                                Wt, Wt1, Wt2, P);
  k_proj<<<dim3(576,2), dim3(256), 0, stream>>>(src, Wt, P, out, Qw, Kw, Vb);
  k_vt  <<<dim3(36,16), dim3(256), 0, stream>>>(Vb, Vt);
  k_attn<<<dim3(576),   dim3(256), 0, stream>>>(Qw, Kw, Vt, Qw);
  k_out <<<dim3(576),   dim3(256), 0, stream>>>(Qw, Wt1, P, Wt2, src, out);
}

// Round 16
// 307.456 us; speedup vs baseline: 1.0897x; 1.0897x over previous
//
#include <hip/hip_runtime.h>

typedef short s8v __attribute__((ext_vector_type(8)));
typedef float f4v __attribute__((ext_vector_type(4)));

#define MFMA16(a,b,c) __builtin_amdgcn_mfma_f32_16x16x32_bf16(a,b,c,0,0,0)

#define TOK 36864
#define SEQ 9216
#define CH 128
#define WL 2304
#define ATTN_SCALE (1.0f/1179648.0f)

__device__ __forceinline__ float b2f(unsigned short u){
  union{unsigned i; float f;} c; c.i = ((unsigned)u)<<16; return c.f;
}
__device__ __forceinline__ unsigned short f2b(float f){
  union{float f; unsigned i;} c; c.f = f;
  unsigned r = c.i + 0x7fffu + ((c.i>>16)&1u);
  return (unsigned short)(r>>16);
}
// window (g,pos) -> token (inverse of the roll+split map)
__device__ __forceinline__ int wtok(int g, int pos){
  int bi = g>>2, ih = (g>>1)&1, iw = g&1;
  int rr = pos/48, ss = pos - rr*48;
  int p = ih*48 + rr, q = iw*48 + ss;
  int i = p + 24; if (i >= 96) i -= 96;
  int j = q + 24; if (j >= 96) j -= 96;
  return bi*SEQ + i*96 + j;
}

// ---------------- K0: weight transpose f32->bf16 + param pack ----------------
__global__ __launch_bounds__(256) void k_prep(const float* __restrict__ wgq,
    const float* __restrict__ wkv, const float* __restrict__ wo1, const float* __restrict__ wo2,
    const float* __restrict__ bgq, const float* __restrict__ bkv, const float* __restrict__ bo1,
    const float* __restrict__ lng, const float* __restrict__ lnb,
    unsigned short* __restrict__ Wt, unsigned short* __restrict__ Wt1,
    unsigned short* __restrict__ Wt2, unsigned short* __restrict__ P)
{
  int idx = blockIdx.x*256 + threadIdx.x;
  if (idx < 65536){
    int n = idx>>7, k = idx&127;
    Wt[idx] = f2b((n<256) ? wgq[k*256+n] : wkv[k*256+(n-256)]);
  } else if (idx < 81920){
    int t2 = idx-65536; int n = t2>>7, k = t2&127;
    Wt1[t2] = f2b(wo1[k*128+n]);
  } else if (idx < 98304){
    int t2 = idx-81920; int n = t2>>7, k = t2&127;
    Wt2[t2] = f2b(wo2[k*128+n]);
  } else if (idx < 99200){
    int j = idx-98304;
    float v;
    if (j<256)      v = bgq[j];
    else if (j<512) v = bkv[j-256];
    else if (j<640) v = bo1[j-512];
    else if (j<768) v = lng[j-640];
    else            v = lnb[j-768];
    P[j] = f2b(v);   // P: [bgq|bkv|bo1|lng|lnb]
  }
}

// ---------------- K1: fused LN + projection GEMM + silu ----------------
// Round 8 version (validated: 66 -> ~35 µs): weight sub-tile staged in a
// XOR-swizzled [128][128] LDS tile (coalesced 1KB/instr loads, swizzled
// b128 fragment reads). Grid (576,2); 2 sub-chunks per block.
__global__ __launch_bounds__(256) void k_proj(const float* __restrict__ src,
    const unsigned short* __restrict__ Wt, const unsigned short* __restrict__ P,
    float* __restrict__ gate, unsigned short* __restrict__ Qw,
    unsigned short* __restrict__ Kw, unsigned short* __restrict__ Vb)
{
  __shared__ __align__(16) short lS[64][136];
  __shared__ __align__(16) short lW[128][128];   // weight sub-tile, swizzled
  const int tid = threadIdx.x;
  const int w = tid>>6, l = tid&63, l16 = l&15, quad = l>>4;
  const int m0 = blockIdx.x*64;
  const int chunk = blockIdx.y;

  { // LayerNorm of 64 rows into LDS (4 threads per row)
    int row = tid>>2, lam = tid&3;
    const float* sp = src + (m0+row)*CH + lam*32;
    float v[32]; float s = 0.f, sq = 0.f;
#pragma unroll
    for (int j=0;j<32;j++){ v[j] = sp[j]; s += v[j]; sq += v[j]*v[j]; }
    s += __shfl_xor(s,1); sq += __shfl_xor(sq,1);
    s += __shfl_xor(s,2); sq += __shfl_xor(sq,2);
    float mean = s*(1.f/128.f);
    float rstd = rsqrtf(sq*(1.f/128.f) - mean*mean + 1e-5f);
#pragma unroll
    for (int j=0;j<32;j++){
      int c = lam*32 + j;
      lS[row][c] = (short)f2b((v[j]-mean)*rstd*b2f(P[640+c]) + b2f(P[768+c]));
    }
  }
  __syncthreads();

  s8v a[4];
#pragma unroll
  for (int kc=0;kc<4;kc++) a[kc] = *(const s8v*)&lS[w*16+l16][kc*32+quad*8];

  int tokv[4], gidx[4], posv[4];
#pragma unroll
  for (int r=0;r<4;r++){
    int token = m0 + w*16 + quad*4 + r;
    int bi = token / SEQ; int t = token - bi*SEQ;
    int i = t / 96; int j = t - i*96;
    int p = i - 24; if (p<0) p += 96;
    int q = j - 24; if (q<0) q += 96;
    int ihh = (p>=48); int rr = p - ihh*48;
    int iww = (q>=48); int ss = q - iww*48;
    tokv[r] = token;
    gidx[r] = bi*4 + ihh*2 + iww;
    posv[r] = rr*48 + ss;
  }

  // weight staging geometry (k_attn lK recipe): rows j*16+kr0, coalesced
  const int kr0 = tid>>4, kc0 = (tid&15)*8;
  const int kws = ((tid&15) ^ (kr0&7))*8;        // swizzled chunk (row&7 == kr0&7)
  const unsigned short* Wsrc = Wt + (chunk*256)*CH;

  for (int sc=0; sc<2; sc++){
    const unsigned short* wp = Wsrc + (sc*128 + kr0)*CH + kc0;
#pragma unroll
    for (int j=0;j<8;j++)
      *(s8v*)&lW[j*16 + kr0][kws] = *(const s8v*)(wp + j*16*CH);
    __syncthreads();

    f4v acc[8];
#pragma unroll
    for (int nt=0;nt<8;nt++){
      f4v z = {0.f,0.f,0.f,0.f}; acc[nt] = z;
#pragma unroll
      for (int kc=0;kc<4;kc++)
        acc[nt] = MFMA16(a[kc],
                         *(const s8v*)&lW[nt*16+l16][((kc*4+quad) ^ (l16&7))*8],
                         acc[nt]);
    }
#pragma unroll
    for (int nt=0;nt<8;nt++){
      int col = chunk*256 + sc*128 + nt*16 + l16;
      float bias = b2f(P[col]);
#pragma unroll
      for (int r=0;r<4;r++){
        float z = acc[nt][r] + bias;
        z = z / (1.0f + __expf(-z));            // silu
        if (col < 128){
          gate[tokv[r]*CH + col] = z;           // f32, parked in d_out
        } else if (col < 256){
          Qw[(gidx[r]*WL + posv[r])*CH + (col-128)] = f2b(z);
        } else if (col < 384){
          Kw[(gidx[r]*WL + posv[r])*CH + (col-256)] = f2b(z);
        } else {
          Vb[tokv[r]*CH + (col-384)] = f2b(z);  // token-layout (k_vt transposes)
        }
      }
    }
    __syncthreads();   // lW reads done before next stage
  }
}

// ---------------- K1b: V token-layout -> windowed V^T [g][ch][pos] ----------------
// Conflict-free LDS transpose (pitch 66 shorts): stage bank=lane, read bank=33*key≡key.
__global__ __launch_bounds__(256) void k_vt(const unsigned short* __restrict__ Vb,
    unsigned short* __restrict__ Vt)
{
  __shared__ short lR[64*66];
  const int tid = threadIdx.x;
  const int g = blockIdx.y;
  const int q0 = blockIdx.x*64;
  const int lane = tid&63, grp = tid>>6;
#pragma unroll 4
  for (int p=0;p<16;p++){
    int key = p*4 + grp;
    int token = wtok(g, q0+key);
    unsigned v = *(const unsigned*)(Vb + token*CH + lane*2);   // 2 ch per lane
    *(unsigned*)&lR[key*66 + lane*2] = v;
  }
  __syncthreads();
#pragma unroll 8
  for (int i=0;i<32;i++){
    int ch = grp*32 + i;
    Vt[g*CH*WL + ch*WL + q0 + lane] = (unsigned short)lR[lane*66 + ch];
  }
}

// ---------------- K2: windowed attention, BM=64 (round-14 version: best verified) ----------------
// 40 KB LDS / 2.25 blocks/CU / 9 waves/CU is the occupancy sweet spot —
// confirmed by three failed alternatives (r3 global-K, r4/r5 fragment-sharing,
// r15 double-buffer; each lost more occupancy than it gained elsewhere).
//  (a) XOR-swizzled LDS tiles; (b) s_setprio around MFMA clusters;
//  (c) rule-#18 fence after the lP wave-drain (race proven & fixed in r12).
// attn aliases Qw: each block reads exactly the Q rows it later writes.
__global__ __launch_bounds__(256, 3) void k_attn(const unsigned short* Qw,
    const unsigned short* __restrict__ Kw, const unsigned short* __restrict__ Vt,
    unsigned short* attn)
{
  __shared__ __align__(16) short lK[64][128];   // K tile [key][ch], swizzled
  __shared__ __align__(16) short lV[128][64];   // V tile [ch][key], swizzled
  __shared__ __align__(16) short lP[4][16][64]; // per-wave P [row][key], swizzled
  const int tid = threadIdx.x;
  const int w = tid>>6, l = tid&63, l16 = l&15, quad = l>>4;

  // XCD swizzle: bijective since 576 % 8 == 0
  const int n  = blockIdx.x;
  const int L  = (n & 7)*72 + (n >> 3);
  const int g  = L/36;
  const int q0 = (L - g*36)*64;
  const int ih = (g>>1)&1, iw = g&1;

  const unsigned short* qp = Qw + (g*WL + q0 + w*16 + l16)*CH + quad*8;
  s8v aQ[4];
#pragma unroll
  for (int kc=0;kc<4;kc++) aQ[kc] = *(const s8v*)(qp + kc*32);

  int qrl[4], qcl[4];
#pragma unroll
  for (int r=0;r<4;r++){
    int qpj = q0 + w*16 + quad*4 + r;
    int qr = qpj/48, qs = qpj - qr*48;
    qrl[r] = (qr>=24); qcl[r] = (qs>=24);
  }

  // staging geometry + swizzled LDS chunk indices (constant per thread)
  const int kr0 = tid>>4, kc0 = (tid&15)*8;        // K: rows kr0+it*16, global chans kc0..+7
  const int vc0 = tid>>3, vp0 = (tid&7)*8;         // V: chans vc0+it*32, global keys vp0..+7
  const int kws = ((tid&15) ^ (kr0&7))*8;          // lK swizzled short offset (row&7 == kr0&7)
  const int vws = ((tid&7)  ^ (vc0&7))*8;          // lV swizzled short offset (row&7 == vc0&7)
  const unsigned short* Kbase = Kw + g*WL*CH;
  const unsigned short* Vbase = Vt + g*CH*WL;
  s8v rK[4], rV[4];

#define LOAD_TILE(kk) do { \
    const unsigned short* Kg_ = Kbase + (kk)*CH; \
    const unsigned short* Vg_ = Vbase + (kk); \
    rK[0] = *(const s8v*)(Kg_ + (kr0+ 0)*CH + kc0); \
    rK[1] = *(const s8v*)(Kg_ + (kr0+16)*CH + kc0); \
    rK[2] = *(const s8v*)(Kg_ + (kr0+32)*CH + kc0); \
    rK[3] = *(const s8v*)(Kg_ + (kr0+48)*CH + kc0); \
    rV[0] = *(const s8v*)(Vg_ + (vc0+ 0)*WL + vp0); \
    rV[1] = *(const s8v*)(Vg_ + (vc0+32)*WL + vp0); \
    rV[2] = *(const s8v*)(Vg_ + (vc0+64)*WL + vp0); \
    rV[3] = *(const s8v*)(Vg_ + (vc0+96)*WL + vp0); \
  } while(0)

#define WRITE_TILE() do { \
    *(s8v*)&lK[kr0+ 0][kws] = rK[0]; \
    *(s8v*)&lK[kr0+16][kws] = rK[1]; \
    *(s8v*)&lK[kr0+32][kws] = rK[2]; \
    *(s8v*)&lK[kr0+48][kws] = rK[3]; \
    *(s8v*)&lV[vc0+ 0][vws] = rV[0]; \
    *(s8v*)&lV[vc0+32][vws] = rV[1]; \
    *(s8v*)&lV[vc0+64][vws] = rV[2]; \
    *(s8v*)&lV[vc0+96][vws] = rV[3]; \
  } while(0)

  f4v O[8];
#pragma unroll
  for (int i=0;i<8;i++){ f4v z = {0.f,0.f,0.f,0.f}; O[i] = z; }
  float lsum[4] = {0.f,0.f,0.f,0.f};

  LOAD_TILE(0);

  for (int k0=0; k0<WL; k0+=64){
    __syncthreads();      // previous tile fully consumed -> LDS safe to overwrite
    WRITE_TILE();         // implicit vmcnt wait; loads had a full compute phase
    __syncthreads();      // tile visible to all waves
    if (k0+64 < WL) LOAD_TILE(k0+64);   // issue next tile; lands during compute

    f4v S[4];
    __builtin_amdgcn_s_setprio(1);
#pragma unroll
    for (int nt=0;nt<4;nt++){
      f4v z = {0.f,0.f,0.f,0.f}; S[nt] = z;
#pragma unroll
      for (int kc=0;kc<4;kc++)
        S[nt] = MFMA16(aQ[kc],
                       *(const s8v*)&lK[nt*16+l16][((kc*4+quad) ^ (l16&7))*8],
                       S[nt]);
    }
    __builtin_amdgcn_s_setprio(0);

#pragma unroll
    for (int nt=0;nt<4;nt++){
      int key = k0 + nt*16 + l16;
      int kr = key/48, ks = key - kr*48;
      int krl = (kr>=24), kcl = (ks>=24);
#pragma unroll
      for (int r=0;r<4;r++){
        bool masked = (ih && (krl != qrl[r])) || (iw && (kcl != qcl[r]));
        float p = masked ? 0.0f : __expf(S[nt][r]*ATTN_SCALE);
        unsigned short pb = f2b(p);
        lsum[r] += b2f(pb);
        // element (row=quad*4+r, key short s=nt*16+l16) at chunk (s>>3)^(row&7)
        lP[w][quad*4+r][(((nt*2)+(l16>>3)) ^ ((quad*4+r)&7))*8 + (l16&7)] = (short)pb;
      }
    }
    // P is wave-private: drain LDS writes, then fence the scheduler (rule #18)
    asm volatile("s_waitcnt lgkmcnt(0)" ::: "memory");
    __builtin_amdgcn_sched_barrier(0);

    __builtin_amdgcn_s_setprio(1);
#pragma unroll
    for (int kc2=0;kc2<2;kc2++){
      s8v aP = *(const s8v*)&lP[w][l16][((kc2*4+quad) ^ (l16&7))*8];
#pragma unroll
      for (int nt=0;nt<8;nt++)
        O[nt] = MFMA16(aP,
                       *(const s8v*)&lV[nt*16+l16][((kc2*4+quad) ^ (l16&7))*8],
                       O[nt]);
    }
    __builtin_amdgcn_s_setprio(0);
  }

#undef LOAD_TILE
#undef WRITE_TILE

#pragma unroll
  for (int r=0;r<4;r++){
#pragma unroll
    for (int m=1;m<16;m<<=1) lsum[r] += __shfl_xor(lsum[r], m);
  }
  unsigned short* outp = attn + (g*WL + q0 + w*16)*CH;
#pragma unroll
  for (int nt=0;nt<8;nt++){
#pragma unroll
    for (int r=0;r<4;r++)
      outp[(quad*4+r)*CH + nt*16 + l16] = f2b(O[nt][r] / lsum[r]);
  }
}

// ---------------- K3: unwindow + gate + o1(silu) + o2 + residual (f32 out) ----------------
// Round 14 version (banked: staged weights, full barriers around the lW
// rewrite; passed with fenced k_attn).
__global__ __launch_bounds__(256) void k_out(const unsigned short* __restrict__ attn,
    const unsigned short* __restrict__ Wo1, const unsigned short* __restrict__ P,
    const unsigned short* __restrict__ Wo2, const float* __restrict__ src,
    float* out)
{
  __shared__ __align__(16) short lA[64][136];
  __shared__ __align__(16) short lU[4][16][136];
  __shared__ __align__(16) short lW[128][128];   // weight tile, swizzled (Wo1 then Wo2)
  const int tid = threadIdx.x;
  const int w = tid>>6, l = tid&63, l16 = l&15, quad = l>>4;
  const int m0 = blockIdx.x*64;

  // weight staging geometry (r8-validated recipe)
  const int kr0 = tid>>4, kc0 = (tid&15)*8;
  const int kws = ((tid&15) ^ (kr0&7))*8;        // swizzled chunk (row&7 == kr0&7)

  {
    int r_loc = tid>>2;
    int cb = (tid&3)*32;
    int token = m0 + r_loc;
    int bi = token / SEQ; int t = token - bi*SEQ;
    int i = t / 96; int j = t - i*96;
    int p = i - 24; if (p<0) p += 96;
    int q = j - 24; if (q<0) q += 96;
    int ihh = (p>=48); int rr = p - ihh*48;
    int iww = (q>=48); int ss = q - iww*48;
    int wb = (bi*4 + ihh*2 + iww)*WL + rr*48 + ss;
    const unsigned short* av = attn + wb*CH + cb;
    const float* gv = out + token*CH + cb;    // gate parked in out[0:TOK*CH)
#pragma unroll
    for (int u=0;u<4;u++){
      s8v a8 = *(const s8v*)(av + u*8);
      float4 g0 = *(const float4*)(gv + u*8);
      float4 g1 = *(const float4*)(gv + u*8 + 4);
      s8v o;
      o[0]=(short)f2b(b2f((unsigned short)a8[0])*g0.x);
      o[1]=(short)f2b(b2f((unsigned short)a8[1])*g0.y);
      o[2]=(short)f2b(b2f((unsigned short)a8[2])*g0.z);
      o[3]=(short)f2b(b2f((unsigned short)a8[3])*g0.w);
      o[4]=(short)f2b(b2f((unsigned short)a8[4])*g1.x);
      o[5]=(short)f2b(b2f((unsigned short)a8[5])*g1.y);
      o[6]=(short)f2b(b2f((unsigned short)a8[6])*g1.z);
      o[7]=(short)f2b(b2f((unsigned short)a8[7])*g1.w);
      *(s8v*)&lA[r_loc][cb + u*8] = o;
    }
  }
  { // stage Wo1 into lW (coalesced 1KB/instr, swizzled dest)
    const unsigned short* wp = Wo1 + kr0*CH + kc0;
#pragma unroll
    for (int j=0;j<8;j++)
      *(s8v*)&lW[j*16 + kr0][kws] = *(const s8v*)(wp + j*16*CH);
  }
  __syncthreads();

  s8v aA[4];
#pragma unroll
  for (int kc=0;kc<4;kc++) aA[kc] = *(const s8v*)&lA[w*16+l16][kc*32+quad*8];
  f4v acc[8];
#pragma unroll
  for (int nt=0;nt<8;nt++){
    f4v z = {0.f,0.f,0.f,0.f}; acc[nt] = z;
#pragma unroll
    for (int kc=0;kc<4;kc++)
      acc[nt] = MFMA16(aA[kc],
                       *(const s8v*)&lW[nt*16+l16][((kc*4+quad) ^ (l16&7))*8],
                       acc[nt]);
  }
#pragma unroll
  for (int nt=0;nt<8;nt++){
    int col = nt*16 + l16;
    float bias = b2f(P[512+col]);   // bo1
#pragma unroll
    for (int r=0;r<4;r++){
      float z = acc[nt][r] + bias;
      z = z / (1.0f + __expf(-z));
      lU[w][quad*4+r][col] = (short)f2b(z);
    }
  }
  __syncthreads();   // all lW(Wo1) reads + lU writes drained (barrier waits lgkmcnt(0))

  { // stage Wo2 into lW (safe: previous reads complete across the barrier)
    const unsigned short* wp = Wo2 + kr0*CH + kc0;
#pragma unroll
    for (int j=0;j<8;j++)
      *(s8v*)&lW[j*16 + kr0][kws] = *(const s8v*)(wp + j*16*CH);
  }
  __syncthreads();   // lW(Wo2) visible

  s8v aU[4];
#pragma unroll
  for (int kc=0;kc<4;kc++) aU[kc] = *(const s8v*)&lU[w][l16][kc*32+quad*8];
  f4v acc2[8];
#pragma unroll
  for (int nt=0;nt<8;nt++){
    f4v z = {0.f,0.f,0.f,0.f}; acc2[nt] = z;
#pragma unroll
    for (int kc=0;kc<4;kc++)
      acc2[nt] = MFMA16(aU[kc],
                        *(const s8v*)&lW[nt*16+l16][((kc*4+quad) ^ (l16&7))*8],
                        acc2[nt]);
  }
#pragma unroll
  for (int nt=0;nt<8;nt++){
#pragma unroll
    for (int r=0;r<4;r++){
      int token = m0 + w*16 + quad*4 + r;
      int col = nt*16 + l16;
      float y = acc2[nt][r] + src[token*CH + col];
      out[token*CH + col] = y;
      out[TOK*CH + token*CH + col] = y;
    }
  }
}

extern "C" void kernel_launch(void* const* d_in, const int* in_sizes, int n_in,
                              void* d_out, int out_size, void* d_ws, size_t ws_size,
                              hipStream_t stream)
{
  const float* src = (const float*)d_in[0];
  const float* lng = (const float*)d_in[5];
  const float* lnb = (const float*)d_in[6];
  const float* wgq = (const float*)d_in[7];
  const float* bgq = (const float*)d_in[8];
  const float* wkv = (const float*)d_in[9];
  const float* bkv = (const float*)d_in[10];
  const float* wo1 = (const float*)d_in[11];
  const float* bo1 = (const float*)d_in[12];
  const float* wo2 = (const float*)d_in[13];

  // Workspace 36.2 MiB: P | Wt | Wt1 | Wt2 | Qw(attn overlays) | Kw | Vt | Vb
  char* ws = (char*)d_ws;
  unsigned short* P   = (unsigned short*)(ws);
  unsigned short* Wt  = (unsigned short*)(ws + 2048);
  unsigned short* Wt1 = (unsigned short*)(ws + 133120);
  unsigned short* Wt2 = (unsigned short*)(ws + 165888);
  unsigned short* Qw  = (unsigned short*)(ws + 198656);    // window layout
  unsigned short* Kw  = (unsigned short*)(ws + 9635840);   // window layout
  unsigned short* Vt  = (unsigned short*)(ws + 19073024);  // [g][ch][pos]
  unsigned short* Vb  = (unsigned short*)(ws + 28510208);  // token layout
  float* out = (float*)d_out;                              // gate in out[0:TOK*CH)

  k_prep<<<dim3(388),   dim3(256), 0, stream>>>(wgq, wkv, wo1, wo2, bgq, bkv, bo1, lng, lnb,
                                                Wt, Wt1, Wt2, P);
  k_proj<<<dim3(576,2), dim3(256), 0, stream>>>(src, Wt, P, out, Qw, Kw, Vb);
  k_vt  <<<dim3(36,16), dim3(256), 0, stream>>>(Vb, Vt);
  k_attn<<<dim3(576),   dim3(256), 0, stream>>>(Qw, Kw, Vt, Qw);
  k_out <<<dim3(576),   dim3(256), 0, stream>>>(Qw, Wt1, P, Wt2, src, out);
}